// Round 3
// baseline (362.179 us; speedup 1.0000x reference)
//
#include <hip/hip_runtime.h>

// ---------------------------------------------------------------------------
// SelfAttention fused pipeline for MI355X (gfx950)
// B=4 S=1024 DIM=2048 H=16 KV=4 HD=128 ROPE_DIM=64
//
// Stages (all on `stream`):
//  1) cast fp32 -> bf16 (x, Wq|Wk|Wv concat, Wproj)
//  2) gemm_bt: qkv[4096x3072] = xb @ Wcat^T            (bf16 in, bf16 out)
//  3) normrope: RMSNorm + partial RoPE in-place on q,k head rows
//  3b) vtrans: V -> Vt_global[b,kvh][d][kv] (pre-swizzled for LDS staging)
//  4) attn_fwd: causal flash attention + v-proj correction -> y bf16
//     (128-row q-tiles, 8 waves, shared K/V staging, heavy-first)
//  5) gemm_bt: out[4096x2048] = y @ Wproj^T            (bf16 in, fp32 out)
// ---------------------------------------------------------------------------

typedef __attribute__((ext_vector_type(8))) __bf16 bf16x8;
typedef __attribute__((ext_vector_type(4))) __bf16 bf16x4;
typedef __attribute__((ext_vector_type(4))) float f32x4;

static_assert(sizeof(__bf16) == 2, "bf16 size");

#define MFMA16x16x32(a, b, c) __builtin_amdgcn_mfma_f32_16x16x32_bf16((a), (b), (c), 0, 0, 0)

__device__ __forceinline__ void gload_lds16(const void* g, void* l) {
  __builtin_amdgcn_global_load_lds((const __attribute__((address_space(1))) void*)g,
                                   (__attribute__((address_space(3))) void*)l, 16, 0, 0);
}

// ---------------- 1) cast fp32 -> bf16 (vectorized) ----------------
__global__ __launch_bounds__(256) void cast_f2b(const float* __restrict__ in,
                                                __bf16* __restrict__ out, int n4) {
  int i = blockIdx.x * blockDim.x + threadIdx.x;
  const int stride = gridDim.x * blockDim.x;
  for (; i < n4; i += stride) {
    f32x4 v = ((const f32x4*)in)[i];
    bf16x4 o;
    o[0] = (__bf16)v[0];
    o[1] = (__bf16)v[1];
    o[2] = (__bf16)v[2];
    o[3] = (__bf16)v[3];
    ((bf16x4*)out)[i] = o;
  }
}

// ---------------- 2/5) B^T GEMM, m97 structure ----------------
template <typename CT>
__global__ __launch_bounds__(256) void gemm_bt(const __bf16* __restrict__ A,
                                               const __bf16* __restrict__ B,
                                               CT* __restrict__ C, int M, int N, int K) {
  __shared__ __bf16 As[128 * 32];
  __shared__ __bf16 Bs[128 * 32];
  const int t = threadIdx.x;
  const int l = t & 63, w = t >> 6;
  const int wr = w >> 1, wc = w & 1;
  const int lr = l & 15, lk = l >> 4;
  const int bm = blockIdx.x, bn = blockIdx.y;
  const __bf16* Ab = A + (size_t)bm * 128 * K;
  const __bf16* Bb = B + (size_t)bn * 128 * K;
  const int srow = t >> 2;
  const int scol = (t & 3) << 3;
  f32x4 acc[4][4] = {};

  for (int k0 = 0; k0 < K; k0 += 32) {
    __syncthreads();
    gload_lds16(Ab + (size_t)srow * K + k0 + scol, As + t * 8);
    gload_lds16(Ab + (size_t)(srow + 64) * K + k0 + scol, As + 2048 + t * 8);
    gload_lds16(Bb + (size_t)srow * K + k0 + scol, Bs + t * 8);
    gload_lds16(Bb + (size_t)(srow + 64) * K + k0 + scol, Bs + 2048 + t * 8);
    __syncthreads();

    bf16x8 af[4], bf[4];
#pragma unroll
    for (int m = 0; m < 4; ++m)
      af[m] = *(const bf16x8*)&As[(wr * 64 + m * 16 + lr) * 32 + lk * 8];
#pragma unroll
    for (int n = 0; n < 4; ++n)
      bf[n] = *(const bf16x8*)&Bs[(wc * 64 + n * 16 + lr) * 32 + lk * 8];
#pragma unroll
    for (int m = 0; m < 4; ++m)
#pragma unroll
      for (int n = 0; n < 4; ++n) acc[m][n] = MFMA16x16x32(af[m], bf[n], acc[m][n]);
  }

#pragma unroll
  for (int m = 0; m < 4; ++m) {
    const int row0 = bm * 128 + wr * 64 + m * 16 + lk * 4;
#pragma unroll
    for (int n = 0; n < 4; ++n) {
      const int col = bn * 128 + wc * 64 + n * 16 + lr;
#pragma unroll
      for (int i = 0; i < 4; ++i) C[(size_t)(row0 + i) * N + col] = (CT)acc[m][n][i];
    }
  }
}

// ---------------- 3) RMSNorm + partial RoPE (in place on qkv) ----------------
__global__ __launch_bounds__(256) void normrope(__bf16* __restrict__ qkv) {
  const int w = threadIdx.x >> 6, l = threadIdx.x & 63;
  const int idx = blockIdx.x * 4 + w;
  int m, col0;
  if (idx < 65536) {
    m = idx >> 4;
    col0 = (idx & 15) << 7;
  } else {
    const int j = idx - 65536;
    m = j >> 2;
    col0 = 2048 + ((j & 3) << 7);
  }
  const int s = m & 1023;
  __bf16* p = qkv + (size_t)m * 3072 + col0;
  float v0 = (float)p[l];
  float v1 = (float)p[l + 64];
  float ss = v0 * v0 + v1 * v1;
#pragma unroll
  for (int off = 1; off < 64; off <<= 1) ss += __shfl_xor(ss, off);
  const float sc = rsqrtf(ss * (1.0f / 128.0f) + 1.1920928955078125e-07f);
  v0 *= sc;
  v1 *= sc;
  const float other = __shfl_xor(v0, 32);
  const int j = l & 31;
  const float ang = (float)s * powf(10000.0f, -(float)j * 0.03125f);
  const float cs = cosf(ang), sn = sinf(ang);
  float r0;
  if (l < 32)
    r0 = v0 * cs + other * sn;
  else
    r0 = -other * sn + v0 * cs;
  p[l] = (__bf16)r0;
  p[l + 64] = (__bf16)v1;
}

// ---------------- 3b) V transpose: Vt[b,kvh][d][kv ^ ((d&7)<<3)] -------------
__global__ __launch_bounds__(256) void vtrans(const __bf16* __restrict__ qkv,
                                              __bf16* __restrict__ vt) {
  __shared__ __bf16 L[64 * 128];
  const int tile = blockIdx.x;  // (b*4+kvh)*16 + st
  const int st = tile & 15, bk = tile >> 4;
  const int b = bk >> 2, kvh = bk & 3;
  const int t = threadIdx.x;
  const int s0 = st * 64;
  const __bf16* src = qkv + ((size_t)(b * 1024 + s0)) * 3072 + 2560 + kvh * 128;
#pragma unroll
  for (int r = 0; r < 4; ++r) {
    const int off = r * 2048 + t * 8;
    const int s = off >> 7, d = off & 127;
    bf16x8 v = *(const bf16x8*)(src + (size_t)s * 3072 + d);
    *(bf16x8*)&L[s * 128 + (d ^ ((s & 7) << 3) ^ (((s >> 3) & 7) << 3))] = v;
  }
  __syncthreads();
  __bf16* dst = vt + (size_t)bk * 128 * 1024;
#pragma unroll
  for (int r = 0; r < 4; ++r) {
    const int off = r * 2048 + t * 8;
    const int d = off >> 6, sc = off & 63;
    bf16x8 v;
#pragma unroll
    for (int j = 0; j < 8; ++j) {
      const int s = sc + j;
      v[j] = L[s * 128 + (d ^ ((s & 7) << 3) ^ (((s >> 3) & 7) << 3))];
    }
    *(bf16x8*)&dst[(size_t)d * 1024 + ((s0 + sc) ^ ((d & 7) << 3))] = v;
  }
}

// ---------------- 4) causal flash attention + v-projection correction ------
// Block: 128 q-rows of one (b,h); 8 waves x 16 q-rows share K/V staging.
// Q in registers; K/V^T/P in XOR-swizzled LDS (b128 reads conflict-free).
__global__ __launch_bounds__(512, 6) void attn_fwd(const __bf16* __restrict__ qkv,
                                                   const __bf16* __restrict__ vt,
                                                   __bf16* __restrict__ y) {
  const int qt = 7 - blockIdx.x;  // heavy blocks dispatch first
  const int h = blockIdx.y, b = blockIdx.z;
  const int kvh = h >> 2;
  const int q0 = qt * 128;
  const int t = threadIdx.x;
  const int l = t & 63, w = t >> 6;  // 8 waves
  const int lr = l & 15, lk = l >> 4;
  const int lr8 = lr & 7;

  __shared__ __bf16 Ks[64 * 128];
  __shared__ __bf16 Vs[128 * 64];
  __shared__ __bf16 Ps[8][16 * 64];

  const size_t rb = (size_t)b * 1024;

  // Q fragments -> registers (one-time); wave w owns q-rows q0+w*16..+15
  bf16x8 aq[4];
  {
    const __bf16* qrow = qkv + (rb + q0 + w * 16 + lr) * 3072 + h * 128 + lk * 8;
#pragma unroll
    for (int kk = 0; kk < 4; ++kk) aq[kk] = *(const bf16x8*)(qrow + kk * 32);
  }

  float m_i[4], l_i[4];
  f32x4 o[8] = {};
#pragma unroll
  for (int i = 0; i < 4; ++i) {
    m_i[i] = -1e30f;
    l_i[i] = 0.0f;
  }

  const float scale = 0.08838834764831843f;  // 1/sqrt(128)
  const int rowg0 = q0 + w * 16 + lk * 4;
  const int wmax = q0 + w * 16 + 15;  // wave's highest q-row
  const __bf16* Vtb = vt + (size_t)(b * 4 + kvh) * 128 * 1024;

  for (int kv0 = 0; kv0 <= q0 + 64; kv0 += 64) {
    __syncthreads();  // prior tile's LDS reads done
    // stage K (source-swizzled -> linear LDS = swizzled layout), 2 rounds
    const __bf16* Kg = qkv + (rb + kv0) * 3072 + 2048 + kvh * 128;
#pragma unroll
    for (int r = 0; r < 2; ++r) {
      const int off = r * 4096 + t * 8;
      const int row = off >> 7;
      const int col = (off & 127) ^ ((row & 7) << 3);
      gload_lds16(Kg + (size_t)row * 3072 + col, Ks + off);
    }
    // stage V^T (pre-swizzled in global), 2 rounds
#pragma unroll
    for (int r = 0; r < 2; ++r) {
      const int off = r * 4096 + t * 8;
      gload_lds16(Vtb + (size_t)(off >> 6) * 1024 + kv0 + (off & 63), Vs + off);
    }
    __syncthreads();  // staging complete

    if (kv0 > wmax) continue;  // wave entirely above diagonal: skip compute

    // S = Q K^T (this wave's 16 q-rows)
    f32x4 sacc[4] = {};
#pragma unroll
    for (int kk = 0; kk < 4; ++kk) {
#pragma unroll
      for (int n = 0; n < 4; ++n) {
        const bf16x8 bk =
            *(const bf16x8*)&Ks[(n * 16 + lr) * 128 + ((kk * 32 + lk * 8) ^ (lr8 << 3))];
        sacc[n] = MFMA16x16x32(aq[kk], bk, sacc[n]);
      }
    }

    // scale + causal mask + online softmax (in-place in sacc)
    float pm[4];
#pragma unroll
    for (int i = 0; i < 4; ++i) pm[i] = -1e30f;
#pragma unroll
    for (int n = 0; n < 4; ++n) {
      const int colg = kv0 + n * 16 + lr;
#pragma unroll
      for (int i = 0; i < 4; ++i) {
        float vsc = sacc[n][i] * scale;
        if (colg > rowg0 + i) vsc = -1e30f;
        sacc[n][i] = vsc;
        pm[i] = fmaxf(pm[i], vsc);
      }
    }
#pragma unroll
    for (int i = 0; i < 4; ++i) {
      pm[i] = fmaxf(pm[i], __shfl_xor(pm[i], 1));
      pm[i] = fmaxf(pm[i], __shfl_xor(pm[i], 2));
      pm[i] = fmaxf(pm[i], __shfl_xor(pm[i], 4));
      pm[i] = fmaxf(pm[i], __shfl_xor(pm[i], 8));
    }
    float alpha[4], rs[4];
#pragma unroll
    for (int i = 0; i < 4; ++i) {
      const float mn = fmaxf(m_i[i], pm[i]);
      alpha[i] = __expf(m_i[i] - mn);
      m_i[i] = mn;
      rs[i] = 0.0f;
    }
#pragma unroll
    for (int n = 0; n < 4; ++n) {
#pragma unroll
      for (int i = 0; i < 4; ++i) {
        const float p = __expf(sacc[n][i] - m_i[i]);
        rs[i] += p;
        const int prow = lk * 4 + i;
        Ps[w][prow * 64 + ((n * 16 + lr) ^ ((prow & 7) << 3))] = (__bf16)p;
      }
    }
#pragma unroll
    for (int i = 0; i < 4; ++i) {
      rs[i] += __shfl_xor(rs[i], 1);
      rs[i] += __shfl_xor(rs[i], 2);
      rs[i] += __shfl_xor(rs[i], 4);
      rs[i] += __shfl_xor(rs[i], 8);
      l_i[i] = l_i[i] * alpha[i] + rs[i];
    }
#pragma unroll
    for (int f = 0; f < 8; ++f)
#pragma unroll
      for (int i = 0; i < 4; ++i) o[f][i] *= alpha[i];

    // O += P V  (P from per-wave swizzled LDS; V^T swizzled in Vs)
#pragma unroll
    for (int ks = 0; ks < 2; ++ks) {
      const bf16x8 pa = *(const bf16x8*)&Ps[w][lr * 64 + ((ks * 32 + lk * 8) ^ (lr8 << 3))];
#pragma unroll
      for (int f = 0; f < 8; ++f) {
        const bf16x8 vb =
            *(const bf16x8*)&Vs[(f * 16 + lr) * 64 + ((ks * 32 + lk * 8) ^ (lr8 << 3))];
        o[f] = MFMA16x16x32(pa, vb, o[f]);
      }
    }
  }

  // epilogue: normalize, v-projection correction, store bf16
#pragma unroll
  for (int i = 0; i < 4; ++i) {
    const int sg = rowg0 + i;
    const size_t mg = rb + sg;
    const __bf16* vp = qkv + mg * 3072 + 2560 + kvh * 128;
    const float invl = 1.0f / l_i[i];
    float vvv[8], yvv[8];
    float dyv = 0.0f, dvv = 0.0f;
#pragma unroll
    for (int f = 0; f < 8; ++f) {
      const float vf = (float)vp[f * 16 + lr];
      const float yf = o[f][i] * invl;
      vvv[f] = vf;
      yvv[f] = yf;
      dyv += yf * vf;
      dvv += vf * vf;
    }
#pragma unroll
    for (int off = 1; off < 16; off <<= 1) {
      dyv += __shfl_xor(dyv, off);
      dvv += __shfl_xor(dvv, off);
    }
    const float proj = dyv / fmaxf(dvv, 1e-6f);
    __bf16* yp = y + mg * 2048 + h * 128;
#pragma unroll
    for (int f = 0; f < 8; ++f) yp[f * 16 + lr] = (__bf16)(yvv[f] - proj * vvv[f]);
  }
}

// ---------------------------------------------------------------------------
extern "C" void kernel_launch(void* const* d_in, const int* in_sizes, int n_in,
                              void* d_out, int out_size, void* d_ws, size_t ws_size,
                              hipStream_t stream) {
  const float* x = (const float*)d_in[0];
  const float* Wq = (const float*)d_in[2];
  const float* Wk = (const float*)d_in[3];
  const float* Wv = (const float*)d_in[4];
  const float* Wp = (const float*)d_in[5];
  float* out = (float*)d_out;

  __bf16* xb = (__bf16*)d_ws;                // 4096x2048
  __bf16* Wb = xb + (size_t)4096 * 2048;     // 3072x2048  [Wq;Wk;Wv]
  __bf16* Wpb = Wb + (size_t)3072 * 2048;    // 2048x2048
  __bf16* qkv = Wpb + (size_t)2048 * 2048;   // 4096x3072
  __bf16* yb = qkv + (size_t)4096 * 3072;    // 4096x2048
  __bf16* vt = xb;  // reuse xb region after qkv GEMM (4*4*128*1024 elems)

  cast_f2b<<<1024, 256, 0, stream>>>(x, xb, 4096 * 2048 / 4);
  cast_f2b<<<512, 256, 0, stream>>>(Wq, Wb, 2048 * 2048 / 4);
  cast_f2b<<<128, 256, 0, stream>>>(Wk, Wb + (size_t)2048 * 2048, 512 * 2048 / 4);
  cast_f2b<<<128, 256, 0, stream>>>(Wv, Wb + (size_t)2048 * 2048 + (size_t)512 * 2048,
                                    512 * 2048 / 4);
  cast_f2b<<<512, 256, 0, stream>>>(Wp, Wpb, 2048 * 2048 / 4);

  gemm_bt<__bf16><<<dim3(32, 24), 256, 0, stream>>>(xb, Wb, qkv, 4096, 3072, 2048);
  normrope<<<20480, 256, 0, stream>>>(qkv);
  vtrans<<<256, 256, 0, stream>>>(qkv, vt);
  attn_fwd<<<dim3(8, 16, 4), 512, 0, stream>>>(qkv, vt, yb);
  gemm_bt<float><<<dim3(32, 16), 256, 0, stream>>>(yb, Wpb, out, 4096, 2048, 2048);
}

// Round 4
// 262.915 us; speedup vs baseline: 1.3776x; 1.3776x over previous
//
#include <hip/hip_runtime.h>

// ---------------------------------------------------------------------------
// SelfAttention fused pipeline for MI355X (gfx950)
// B=4 S=1024 DIM=2048 H=16 KV=4 HD=128 ROPE_DIM=64
//
// Stages (all on `stream`):
//  1) cast fp32 -> bf16 (x, Wq|Wk|Wv concat, Wproj)
//  2) gemm_bt: qkv[4096x3072] = xb @ Wcat^T            (bf16 in, bf16 out)
//  3) normrope: RMSNorm + partial RoPE in-place on q,k head rows
//  3b) vtrans: V -> Vt_global[b,kvh][d][kv] (pre-swizzled for LDS staging)
//  4) attn_fwd: causal flash attention + v-proj correction -> y bf16
//     (128-row q-tiles, 8 waves; NO min-wave launch bound -> no spills)
//  5) gemm_bt: out[4096x2048] = y @ Wproj^T            (bf16 in, fp32 out)
// ---------------------------------------------------------------------------

typedef __attribute__((ext_vector_type(8))) __bf16 bf16x8;
typedef __attribute__((ext_vector_type(4))) __bf16 bf16x4;
typedef __attribute__((ext_vector_type(4))) float f32x4;

static_assert(sizeof(__bf16) == 2, "bf16 size");

#define MFMA16x16x32(a, b, c) __builtin_amdgcn_mfma_f32_16x16x32_bf16((a), (b), (c), 0, 0, 0)

__device__ __forceinline__ void gload_lds16(const void* g, void* l) {
  __builtin_amdgcn_global_load_lds((const __attribute__((address_space(1))) void*)g,
                                   (__attribute__((address_space(3))) void*)l, 16, 0, 0);
}

// ---------------- 1) cast fp32 -> bf16 (vectorized) ----------------
__global__ __launch_bounds__(256) void cast_f2b(const float* __restrict__ in,
                                                __bf16* __restrict__ out, int n4) {
  int i = blockIdx.x * blockDim.x + threadIdx.x;
  const int stride = gridDim.x * blockDim.x;
  for (; i < n4; i += stride) {
    f32x4 v = ((const f32x4*)in)[i];
    bf16x4 o;
    o[0] = (__bf16)v[0];
    o[1] = (__bf16)v[1];
    o[2] = (__bf16)v[2];
    o[3] = (__bf16)v[3];
    ((bf16x4*)out)[i] = o;
  }
}

// ---------------- 2/5) B^T GEMM, m97 structure ----------------
template <typename CT>
__global__ __launch_bounds__(256) void gemm_bt(const __bf16* __restrict__ A,
                                               const __bf16* __restrict__ B,
                                               CT* __restrict__ C, int M, int N, int K) {
  __shared__ __bf16 As[128 * 32];
  __shared__ __bf16 Bs[128 * 32];
  const int t = threadIdx.x;
  const int l = t & 63, w = t >> 6;
  const int wr = w >> 1, wc = w & 1;
  const int lr = l & 15, lk = l >> 4;
  const int bm = blockIdx.x, bn = blockIdx.y;
  const __bf16* Ab = A + (size_t)bm * 128 * K;
  const __bf16* Bb = B + (size_t)bn * 128 * K;
  const int srow = t >> 2;
  const int scol = (t & 3) << 3;
  f32x4 acc[4][4] = {};

  for (int k0 = 0; k0 < K; k0 += 32) {
    __syncthreads();
    gload_lds16(Ab + (size_t)srow * K + k0 + scol, As + t * 8);
    gload_lds16(Ab + (size_t)(srow + 64) * K + k0 + scol, As + 2048 + t * 8);
    gload_lds16(Bb + (size_t)srow * K + k0 + scol, Bs + t * 8);
    gload_lds16(Bb + (size_t)(srow + 64) * K + k0 + scol, Bs + 2048 + t * 8);
    __syncthreads();

    bf16x8 af[4], bf[4];
#pragma unroll
    for (int m = 0; m < 4; ++m)
      af[m] = *(const bf16x8*)&As[(wr * 64 + m * 16 + lr) * 32 + lk * 8];
#pragma unroll
    for (int n = 0; n < 4; ++n)
      bf[n] = *(const bf16x8*)&Bs[(wc * 64 + n * 16 + lr) * 32 + lk * 8];
#pragma unroll
    for (int m = 0; m < 4; ++m)
#pragma unroll
      for (int n = 0; n < 4; ++n) acc[m][n] = MFMA16x16x32(af[m], bf[n], acc[m][n]);
  }

#pragma unroll
  for (int m = 0; m < 4; ++m) {
    const int row0 = bm * 128 + wr * 64 + m * 16 + lk * 4;
#pragma unroll
    for (int n = 0; n < 4; ++n) {
      const int col = bn * 128 + wc * 64 + n * 16 + lr;
#pragma unroll
      for (int i = 0; i < 4; ++i) C[(size_t)(row0 + i) * N + col] = (CT)acc[m][n][i];
    }
  }
}

// ---------------- 3) RMSNorm + partial RoPE (in place on qkv) ----------------
__global__ __launch_bounds__(256) void normrope(__bf16* __restrict__ qkv) {
  const int w = threadIdx.x >> 6, l = threadIdx.x & 63;
  const int idx = blockIdx.x * 4 + w;
  int m, col0;
  if (idx < 65536) {
    m = idx >> 4;
    col0 = (idx & 15) << 7;
  } else {
    const int j = idx - 65536;
    m = j >> 2;
    col0 = 2048 + ((j & 3) << 7);
  }
  const int s = m & 1023;
  __bf16* p = qkv + (size_t)m * 3072 + col0;
  float v0 = (float)p[l];
  float v1 = (float)p[l + 64];
  float ss = v0 * v0 + v1 * v1;
#pragma unroll
  for (int off = 1; off < 64; off <<= 1) ss += __shfl_xor(ss, off);
  const float sc = rsqrtf(ss * (1.0f / 128.0f) + 1.1920928955078125e-07f);
  v0 *= sc;
  v1 *= sc;
  const float other = __shfl_xor(v0, 32);
  const int j = l & 31;
  const float ang = (float)s * powf(10000.0f, -(float)j * 0.03125f);
  const float cs = cosf(ang), sn = sinf(ang);
  float r0;
  if (l < 32)
    r0 = v0 * cs + other * sn;
  else
    r0 = -other * sn + v0 * cs;
  p[l] = (__bf16)r0;
  p[l + 64] = (__bf16)v1;
}

// ---------------- 3b) V transpose: Vt[b,kvh][d][kv ^ ((d&7)<<3)] -------------
__global__ __launch_bounds__(256) void vtrans(const __bf16* __restrict__ qkv,
                                              __bf16* __restrict__ vt) {
  __shared__ __bf16 L[64 * 128];
  const int tile = blockIdx.x;  // (b*4+kvh)*16 + st
  const int st = tile & 15, bk = tile >> 4;
  const int b = bk >> 2, kvh = bk & 3;
  const int t = threadIdx.x;
  const int s0 = st * 64;
  const __bf16* src = qkv + ((size_t)(b * 1024 + s0)) * 3072 + 2560 + kvh * 128;
#pragma unroll
  for (int r = 0; r < 4; ++r) {
    const int off = r * 2048 + t * 8;
    const int s = off >> 7, d = off & 127;
    bf16x8 v = *(const bf16x8*)(src + (size_t)s * 3072 + d);
    *(bf16x8*)&L[s * 128 + (d ^ ((s & 7) << 3) ^ (((s >> 3) & 7) << 3))] = v;
  }
  __syncthreads();
  __bf16* dst = vt + (size_t)bk * 128 * 1024;
#pragma unroll
  for (int r = 0; r < 4; ++r) {
    const int off = r * 2048 + t * 8;
    const int d = off >> 6, sc = off & 63;
    bf16x8 v;
#pragma unroll
    for (int j = 0; j < 8; ++j) {
      const int s = sc + j;
      v[j] = L[s * 128 + (d ^ ((s & 7) << 3) ^ (((s >> 3) & 7) << 3))];
    }
    *(bf16x8*)&dst[(size_t)d * 1024 + ((s0 + sc) ^ ((d & 7) << 3))] = v;
  }
}

// ---------------- 4) causal flash attention + v-projection correction ------
// Block: 128 q-rows of one (b,h); 8 waves x 16 q-rows share K/V staging.
// Q in registers; K/V^T/P in XOR-swizzled LDS (b128 reads conflict-free).
// NOTE: no min-waves bound — (512,6) capped VGPRs at ~85 and spilled o/aq
// to scratch (252 MB FETCH, 189 us). Let the allocator use ~120 VGPRs.
__global__ __launch_bounds__(512) void attn_fwd(const __bf16* __restrict__ qkv,
                                                const __bf16* __restrict__ vt,
                                                __bf16* __restrict__ y) {
  const int qt = 7 - blockIdx.x;  // heavy blocks dispatch first
  const int h = blockIdx.y, b = blockIdx.z;
  const int kvh = h >> 2;
  const int q0 = qt * 128;
  const int t = threadIdx.x;
  const int l = t & 63, w = t >> 6;  // 8 waves
  const int lr = l & 15, lk = l >> 4;
  const int lr8 = lr & 7;

  __shared__ __bf16 Ks[64 * 128];
  __shared__ __bf16 Vs[128 * 64];
  __shared__ __bf16 Ps[8][16 * 64];

  const size_t rb = (size_t)b * 1024;

  // Q fragments -> registers (one-time); wave w owns q-rows q0+w*16..+15
  bf16x8 aq[4];
  {
    const __bf16* qrow = qkv + (rb + q0 + w * 16 + lr) * 3072 + h * 128 + lk * 8;
#pragma unroll
    for (int kk = 0; kk < 4; ++kk) aq[kk] = *(const bf16x8*)(qrow + kk * 32);
  }

  float m_i[4], l_i[4];
  f32x4 o[8] = {};
#pragma unroll
  for (int i = 0; i < 4; ++i) {
    m_i[i] = -1e30f;
    l_i[i] = 0.0f;
  }

  const float scale = 0.08838834764831843f;  // 1/sqrt(128)
  const int rowg0 = q0 + w * 16 + lk * 4;
  const int wmax = q0 + w * 16 + 15;  // wave's highest q-row
  const __bf16* Vtb = vt + (size_t)(b * 4 + kvh) * 128 * 1024;

  for (int kv0 = 0; kv0 <= q0 + 64; kv0 += 64) {
    __syncthreads();  // prior tile's LDS reads done
    // stage K (source-swizzled -> linear LDS = swizzled layout), 2 rounds
    const __bf16* Kg = qkv + (rb + kv0) * 3072 + 2048 + kvh * 128;
#pragma unroll
    for (int r = 0; r < 2; ++r) {
      const int off = r * 4096 + t * 8;
      const int row = off >> 7;
      const int col = (off & 127) ^ ((row & 7) << 3);
      gload_lds16(Kg + (size_t)row * 3072 + col, Ks + off);
    }
    // stage V^T (pre-swizzled in global), 2 rounds
#pragma unroll
    for (int r = 0; r < 2; ++r) {
      const int off = r * 4096 + t * 8;
      gload_lds16(Vtb + (size_t)(off >> 6) * 1024 + kv0 + (off & 63), Vs + off);
    }
    __syncthreads();  // staging complete

    if (kv0 > wmax) continue;  // wave entirely above diagonal: skip compute

    // S = Q K^T (this wave's 16 q-rows)
    f32x4 sacc[4] = {};
#pragma unroll
    for (int kk = 0; kk < 4; ++kk) {
#pragma unroll
      for (int n = 0; n < 4; ++n) {
        const bf16x8 bk =
            *(const bf16x8*)&Ks[(n * 16 + lr) * 128 + ((kk * 32 + lk * 8) ^ (lr8 << 3))];
        sacc[n] = MFMA16x16x32(aq[kk], bk, sacc[n]);
      }
    }

    // scale + causal mask + online softmax (in-place in sacc)
    float pm[4];
#pragma unroll
    for (int i = 0; i < 4; ++i) pm[i] = -1e30f;
#pragma unroll
    for (int n = 0; n < 4; ++n) {
      const int colg = kv0 + n * 16 + lr;
#pragma unroll
      for (int i = 0; i < 4; ++i) {
        float vsc = sacc[n][i] * scale;
        if (colg > rowg0 + i) vsc = -1e30f;
        sacc[n][i] = vsc;
        pm[i] = fmaxf(pm[i], vsc);
      }
    }
#pragma unroll
    for (int i = 0; i < 4; ++i) {
      pm[i] = fmaxf(pm[i], __shfl_xor(pm[i], 1));
      pm[i] = fmaxf(pm[i], __shfl_xor(pm[i], 2));
      pm[i] = fmaxf(pm[i], __shfl_xor(pm[i], 4));
      pm[i] = fmaxf(pm[i], __shfl_xor(pm[i], 8));
    }
    float alpha[4], rs[4];
#pragma unroll
    for (int i = 0; i < 4; ++i) {
      const float mn = fmaxf(m_i[i], pm[i]);
      alpha[i] = __expf(m_i[i] - mn);
      m_i[i] = mn;
      rs[i] = 0.0f;
    }
#pragma unroll
    for (int n = 0; n < 4; ++n) {
#pragma unroll
      for (int i = 0; i < 4; ++i) {
        const float p = __expf(sacc[n][i] - m_i[i]);
        rs[i] += p;
        const int prow = lk * 4 + i;
        Ps[w][prow * 64 + ((n * 16 + lr) ^ ((prow & 7) << 3))] = (__bf16)p;
      }
    }
#pragma unroll
    for (int i = 0; i < 4; ++i) {
      rs[i] += __shfl_xor(rs[i], 1);
      rs[i] += __shfl_xor(rs[i], 2);
      rs[i] += __shfl_xor(rs[i], 4);
      rs[i] += __shfl_xor(rs[i], 8);
      l_i[i] = l_i[i] * alpha[i] + rs[i];
    }
#pragma unroll
    for (int f = 0; f < 8; ++f)
#pragma unroll
      for (int i = 0; i < 4; ++i) o[f][i] *= alpha[i];

    // O += P V  (P from per-wave swizzled LDS; V^T swizzled in Vs)
#pragma unroll
    for (int ks = 0; ks < 2; ++ks) {
      const bf16x8 pa = *(const bf16x8*)&Ps[w][lr * 64 + ((ks * 32 + lk * 8) ^ (lr8 << 3))];
#pragma unroll
      for (int f = 0; f < 8; ++f) {
        const bf16x8 vb =
            *(const bf16x8*)&Vs[(f * 16 + lr) * 64 + ((ks * 32 + lk * 8) ^ (lr8 << 3))];
        o[f] = MFMA16x16x32(pa, vb, o[f]);
      }
    }
  }

  // epilogue: normalize, v-projection correction, store bf16
#pragma unroll
  for (int i = 0; i < 4; ++i) {
    const int sg = rowg0 + i;
    const size_t mg = rb + sg;
    const __bf16* vp = qkv + mg * 3072 + 2560 + kvh * 128;
    const float invl = 1.0f / l_i[i];
    float vvv[8], yvv[8];
    float dyv = 0.0f, dvv = 0.0f;
#pragma unroll
    for (int f = 0; f < 8; ++f) {
      const float vf = (float)vp[f * 16 + lr];
      const float yf = o[f][i] * invl;
      vvv[f] = vf;
      yvv[f] = yf;
      dyv += yf * vf;
      dvv += vf * vf;
    }
#pragma unroll
    for (int off = 1; off < 16; off <<= 1) {
      dyv += __shfl_xor(dyv, off);
      dvv += __shfl_xor(dvv, off);
    }
    const float proj = dyv / fmaxf(dvv, 1e-6f);
    __bf16* yp = y + mg * 2048 + h * 128;
#pragma unroll
    for (int f = 0; f < 8; ++f) yp[f * 16 + lr] = (__bf16)(yvv[f] - proj * vvv[f]);
  }
}

// ---------------------------------------------------------------------------
extern "C" void kernel_launch(void* const* d_in, const int* in_sizes, int n_in,
                              void* d_out, int out_size, void* d_ws, size_t ws_size,
                              hipStream_t stream) {
  const float* x = (const float*)d_in[0];
  const float* Wq = (const float*)d_in[2];
  const float* Wk = (const float*)d_in[3];
  const float* Wv = (const float*)d_in[4];
  const float* Wp = (const float*)d_in[5];
  float* out = (float*)d_out;

  __bf16* xb = (__bf16*)d_ws;                // 4096x2048
  __bf16* Wb = xb + (size_t)4096 * 2048;     // 3072x2048  [Wq;Wk;Wv]
  __bf16* Wpb = Wb + (size_t)3072 * 2048;    // 2048x2048
  __bf16* qkv = Wpb + (size_t)2048 * 2048;   // 4096x3072
  __bf16* yb = qkv + (size_t)4096 * 3072;    // 4096x2048
  __bf16* vt = xb;  // reuse xb region after qkv GEMM (4*4*128*1024 elems)

  cast_f2b<<<1024, 256, 0, stream>>>(x, xb, 4096 * 2048 / 4);
  cast_f2b<<<512, 256, 0, stream>>>(Wq, Wb, 2048 * 2048 / 4);
  cast_f2b<<<128, 256, 0, stream>>>(Wk, Wb + (size_t)2048 * 2048, 512 * 2048 / 4);
  cast_f2b<<<128, 256, 0, stream>>>(Wv, Wb + (size_t)2048 * 2048 + (size_t)512 * 2048,
                                    512 * 2048 / 4);
  cast_f2b<<<512, 256, 0, stream>>>(Wp, Wpb, 2048 * 2048 / 4);

  gemm_bt<__bf16><<<dim3(32, 24), 256, 0, stream>>>(xb, Wb, qkv, 4096, 3072, 2048);
  normrope<<<20480, 256, 0, stream>>>(qkv);
  vtrans<<<256, 256, 0, stream>>>(qkv, vt);
  attn_fwd<<<dim3(8, 16, 4), 512, 0, stream>>>(qkv, vt, yb);
  gemm_bt<float><<<dim3(32, 16), 256, 0, stream>>>(yb, Wpb, out, 4096, 2048, 2048);
}

// Round 5
// 248.039 us; speedup vs baseline: 1.4602x; 1.0600x over previous
//
#include <hip/hip_runtime.h>

// ---------------------------------------------------------------------------
// SelfAttention fused pipeline for MI355X (gfx950)
// B=4 S=1024 DIM=2048 H=16 KV=4 HD=128 ROPE_DIM=64
//
// Stages (all on `stream`):
//  1) casts fp32 -> bf16 (x | Wq,Wk,Wv fused | Wproj)
//  2) gemm_bt: qkv[4096x3072] = xb @ Wcat^T            (bf16 in, bf16 out)
//  3) normrope: RMSNorm + partial RoPE in-place on q,k head rows
//  3b) vtrans: V -> Vt_global[b,kvh][d][kv] (pre-swizzled for LDS staging)
//  4) attn_fwd: causal flash attention + v-proj correction -> y bf16
//     (128-row q-tiles, 8 waves, K/V double-buffer w/ stage-ahead,
//      XCD-grouped blocks so each (b,kvh)'s K/V is L2-resident,
//      CU-pairing of q-tiles j and 7-j for uniform 18-iter load)
//  5) gemm_bt: out[4096x2048] = y @ Wproj^T            (bf16 in, fp32 out)
// ---------------------------------------------------------------------------

typedef __attribute__((ext_vector_type(8))) __bf16 bf16x8;
typedef __attribute__((ext_vector_type(4))) __bf16 bf16x4;
typedef __attribute__((ext_vector_type(4))) float f32x4;

static_assert(sizeof(__bf16) == 2, "bf16 size");

#define MFMA16x16x32(a, b, c) __builtin_amdgcn_mfma_f32_16x16x32_bf16((a), (b), (c), 0, 0, 0)

__device__ __forceinline__ void gload_lds16(const void* g, void* l) {
  __builtin_amdgcn_global_load_lds((const __attribute__((address_space(1))) void*)g,
                                   (__attribute__((address_space(3))) void*)l, 16, 0, 0);
}

// ---------------- 1) cast fp32 -> bf16 (vectorized) ----------------
__global__ __launch_bounds__(256) void cast_f2b(const float* __restrict__ in,
                                                __bf16* __restrict__ out, int n4) {
  int i = blockIdx.x * blockDim.x + threadIdx.x;
  const int stride = gridDim.x * blockDim.x;
  for (; i < n4; i += stride) {
    f32x4 v = ((const f32x4*)in)[i];
    bf16x4 o;
    o[0] = (__bf16)v[0];
    o[1] = (__bf16)v[1];
    o[2] = (__bf16)v[2];
    o[3] = (__bf16)v[3];
    ((bf16x4*)out)[i] = o;
  }
}

// fused cast of Wq(2048x2048) | Wk(512x2048) | Wv(512x2048) into Wb concat
__global__ __launch_bounds__(256) void cast3_f2b(const float* __restrict__ wq,
                                                 const float* __restrict__ wk,
                                                 const float* __restrict__ wv,
                                                 __bf16* __restrict__ out) {
  const int n1 = 2048 * 2048 / 4, n2 = 512 * 2048 / 4;
  const int ntot = n1 + 2 * n2;
  int i = blockIdx.x * blockDim.x + threadIdx.x;
  const int stride = gridDim.x * blockDim.x;
  for (; i < ntot; i += stride) {
    const float* src;
    int j = i;
    if (j < n1) {
      src = wq;
    } else if (j < n1 + n2) {
      src = wk;
      j -= n1;
    } else {
      src = wv;
      j -= n1 + n2;
    }
    f32x4 v = ((const f32x4*)src)[j];
    bf16x4 o;
    o[0] = (__bf16)v[0];
    o[1] = (__bf16)v[1];
    o[2] = (__bf16)v[2];
    o[3] = (__bf16)v[3];
    ((bf16x4*)out)[i] = o;
  }
}

// ---------------- 2/5) B^T GEMM, m97 structure ----------------
template <typename CT>
__global__ __launch_bounds__(256) void gemm_bt(const __bf16* __restrict__ A,
                                               const __bf16* __restrict__ B,
                                               CT* __restrict__ C, int M, int N, int K) {
  __shared__ __bf16 As[128 * 32];
  __shared__ __bf16 Bs[128 * 32];
  const int t = threadIdx.x;
  const int l = t & 63, w = t >> 6;
  const int wr = w >> 1, wc = w & 1;
  const int lr = l & 15, lk = l >> 4;
  const int bm = blockIdx.x, bn = blockIdx.y;
  const __bf16* Ab = A + (size_t)bm * 128 * K;
  const __bf16* Bb = B + (size_t)bn * 128 * K;
  const int srow = t >> 2;
  const int scol = (t & 3) << 3;
  f32x4 acc[4][4] = {};

  for (int k0 = 0; k0 < K; k0 += 32) {
    __syncthreads();
    gload_lds16(Ab + (size_t)srow * K + k0 + scol, As + t * 8);
    gload_lds16(Ab + (size_t)(srow + 64) * K + k0 + scol, As + 2048 + t * 8);
    gload_lds16(Bb + (size_t)srow * K + k0 + scol, Bs + t * 8);
    gload_lds16(Bb + (size_t)(srow + 64) * K + k0 + scol, Bs + 2048 + t * 8);
    __syncthreads();

    bf16x8 af[4], bf[4];
#pragma unroll
    for (int m = 0; m < 4; ++m)
      af[m] = *(const bf16x8*)&As[(wr * 64 + m * 16 + lr) * 32 + lk * 8];
#pragma unroll
    for (int n = 0; n < 4; ++n)
      bf[n] = *(const bf16x8*)&Bs[(wc * 64 + n * 16 + lr) * 32 + lk * 8];
#pragma unroll
    for (int m = 0; m < 4; ++m)
#pragma unroll
      for (int n = 0; n < 4; ++n) acc[m][n] = MFMA16x16x32(af[m], bf[n], acc[m][n]);
  }

#pragma unroll
  for (int m = 0; m < 4; ++m) {
    const int row0 = bm * 128 + wr * 64 + m * 16 + lk * 4;
#pragma unroll
    for (int n = 0; n < 4; ++n) {
      const int col = bn * 128 + wc * 64 + n * 16 + lr;
#pragma unroll
      for (int i = 0; i < 4; ++i) C[(size_t)(row0 + i) * N + col] = (CT)acc[m][n][i];
    }
  }
}

// ---------------- 3) RMSNorm + partial RoPE (in place on qkv) ----------------
__global__ __launch_bounds__(256) void normrope(__bf16* __restrict__ qkv) {
  const int w = threadIdx.x >> 6, l = threadIdx.x & 63;
  const int idx = blockIdx.x * 4 + w;
  int m, col0;
  if (idx < 65536) {
    m = idx >> 4;
    col0 = (idx & 15) << 7;
  } else {
    const int j = idx - 65536;
    m = j >> 2;
    col0 = 2048 + ((j & 3) << 7);
  }
  const int s = m & 1023;
  __bf16* p = qkv + (size_t)m * 3072 + col0;
  float v0 = (float)p[l];
  float v1 = (float)p[l + 64];
  float ss = v0 * v0 + v1 * v1;
#pragma unroll
  for (int off = 1; off < 64; off <<= 1) ss += __shfl_xor(ss, off);
  const float sc = rsqrtf(ss * (1.0f / 128.0f) + 1.1920928955078125e-07f);
  v0 *= sc;
  v1 *= sc;
  const float other = __shfl_xor(v0, 32);
  const int j = l & 31;
  const float ang = (float)s * powf(10000.0f, -(float)j * 0.03125f);
  const float cs = cosf(ang), sn = sinf(ang);
  float r0;
  if (l < 32)
    r0 = v0 * cs + other * sn;
  else
    r0 = -other * sn + v0 * cs;
  p[l] = (__bf16)r0;
  p[l + 64] = (__bf16)v1;
}

// ---------------- 3b) V transpose: Vt[b,kvh][d][kv ^ ((d&7)<<3)] -------------
__global__ __launch_bounds__(256) void vtrans(const __bf16* __restrict__ qkv,
                                              __bf16* __restrict__ vt) {
  __shared__ __bf16 L[64 * 128];
  const int tile = blockIdx.x;  // (b*4+kvh)*16 + st
  const int st = tile & 15, bk = tile >> 4;
  const int b = bk >> 2, kvh = bk & 3;
  const int t = threadIdx.x;
  const int s0 = st * 64;
  const __bf16* src = qkv + ((size_t)(b * 1024 + s0)) * 3072 + 2560 + kvh * 128;
#pragma unroll
  for (int r = 0; r < 4; ++r) {
    const int off = r * 2048 + t * 8;
    const int s = off >> 7, d = off & 127;
    bf16x8 v = *(const bf16x8*)(src + (size_t)s * 3072 + d);
    *(bf16x8*)&L[s * 128 + (d ^ ((s & 7) << 3) ^ (((s >> 3) & 7) << 3))] = v;
  }
  __syncthreads();
  __bf16* dst = vt + (size_t)bk * 128 * 1024;
#pragma unroll
  for (int r = 0; r < 4; ++r) {
    const int off = r * 2048 + t * 8;
    const int d = off >> 6, sc = off & 63;
    bf16x8 v;
#pragma unroll
    for (int j = 0; j < 8; ++j) {
      const int s = sc + j;
      v[j] = L[s * 128 + (d ^ ((s & 7) << 3) ^ (((s >> 3) & 7) << 3))];
    }
    *(bf16x8*)&dst[(size_t)d * 1024 + ((s0 + sc) ^ ((d & 7) << 3))] = v;
  }
}

// ---------------- 4) causal flash attention + v-projection correction ------
// 512 blocks, 1-D grid. Block id -> (b,kvh) group on a fixed XCD (id&7),
// so each XCD's L2 caches only 2 groups' K/V (1 MB). Within an XCD, the
// two consecutive dispatches pair q-tiles j and 7-j -> every CU's two
// blocks sum to exactly 18 kv-iterations (no tail).
// Per block: 128 q-rows, 8 waves x 16 rows; Q in regs; K/V double-buffered
// in swizzled LDS; stage(t+1) issued BEFORE compute(t) so the barrier's
// vmcnt drain lands after ~1.5us of MFMA+softmax (staging latency hidden).
__global__ __launch_bounds__(512) void attn_fwd(const __bf16* __restrict__ qkv,
                                                const __bf16* __restrict__ vt,
                                                __bf16* __restrict__ y) {
  const int id = blockIdx.x;
  const int xcd = id & 7;
  const int rem = id >> 3;     // 0..63
  const int half = rem & 1;
  const int inner = rem >> 1;  // 0..31
  const int g = xcd | (half << 3);  // (b,kvh) group 0..15
  const int b = g >> 2, kvh = g & 3;
  const int h = kvh * 4 + (inner >> 3);
  const int j = inner & 7;
  const int qt = half ? (7 - j) : j;

  const int q0 = qt * 128;
  const int t = threadIdx.x;
  const int l = t & 63, w = t >> 6;  // 8 waves
  const int lr = l & 15, lk = l >> 4;
  const int lr8 = lr & 7;

  __shared__ __bf16 Ks[2][64 * 128];
  __shared__ __bf16 Vs[2][128 * 64];
  __shared__ __bf16 Ps[8][16 * 64];

  const size_t rb = (size_t)b * 1024;
  const __bf16* Kg0 = qkv + rb * 3072 + 2048 + kvh * 128;
  const __bf16* Vtb = vt + (size_t)(b * 4 + kvh) * 128 * 1024;

  // Q fragments -> registers (one-time); wave w owns q-rows q0+w*16..+15
  bf16x8 aq[4];
  {
    const __bf16* qrow = qkv + (rb + q0 + w * 16 + lr) * 3072 + h * 128 + lk * 8;
#pragma unroll
    for (int kk = 0; kk < 4; ++kk) aq[kk] = *(const bf16x8*)(qrow + kk * 32);
  }

  float m_i[4], l_i[4];
  f32x4 o[8] = {};
#pragma unroll
  for (int i = 0; i < 4; ++i) {
    m_i[i] = -1e30f;
    l_i[i] = 0.0f;
  }

  const float scale = 0.08838834764831843f;  // 1/sqrt(128)
  const int rowg0 = q0 + w * 16 + lk * 4;
  const int wmax = q0 + w * 16 + 15;  // wave's highest q-row
  const int nt = 2 * qt + 2;          // kv-tiles for this q-tile

  // K stage addressing: source-swizzled so linear LDS = swizzled layout
  const int koff0 = t * 8;
  const int krow0 = koff0 >> 7;
  const int kcol0 = (koff0 & 127) ^ ((krow0 & 7) << 3);
  const int koff1 = 4096 + t * 8;
  const int krow1 = koff1 >> 7;
  const int kcol1 = (koff1 & 127) ^ ((krow1 & 7) << 3);
  // V stage addressing (pre-swizzled in global)
  const int voff0 = t * 8, voff1 = 4096 + t * 8;

  // prologue: stage tile 0 into buf 0
  gload_lds16(Kg0 + (size_t)krow0 * 3072 + kcol0, &Ks[0][0] + koff0);
  gload_lds16(Kg0 + (size_t)krow1 * 3072 + kcol1, &Ks[0][0] + koff1);
  gload_lds16(Vtb + (size_t)(voff0 >> 6) * 1024 + (voff0 & 63), &Vs[0][0] + voff0);
  gload_lds16(Vtb + (size_t)(voff1 >> 6) * 1024 + (voff1 & 63), &Vs[0][0] + voff1);
  __syncthreads();  // drains vmcnt -> buf0 ready

  for (int tt = 0; tt < nt; ++tt) {
    const int kv0 = tt * 64;
    const int cur = tt & 1;
    // issue next tile's staging first (async; lands in other buffer)
    if (tt + 1 < nt) {
      const int nkv = kv0 + 64;
      const __bf16* Kg = Kg0 + (size_t)nkv * 3072;
      __bf16* kd = &Ks[cur ^ 1][0];
      __bf16* vd = &Vs[cur ^ 1][0];
      gload_lds16(Kg + (size_t)krow0 * 3072 + kcol0, kd + koff0);
      gload_lds16(Kg + (size_t)krow1 * 3072 + kcol1, kd + koff1);
      gload_lds16(Vtb + (size_t)(voff0 >> 6) * 1024 + nkv + (voff0 & 63), vd + voff0);
      gload_lds16(Vtb + (size_t)(voff1 >> 6) * 1024 + nkv + (voff1 & 63), vd + voff1);
    }

    if (kv0 <= wmax) {  // wave has unmasked work in this tile
      // S = Q K^T (this wave's 16 q-rows)
      f32x4 sacc[4] = {};
#pragma unroll
      for (int kk = 0; kk < 4; ++kk) {
#pragma unroll
        for (int n = 0; n < 4; ++n) {
          const bf16x8 bk = *(const bf16x8*)&Ks[cur][(n * 16 + lr) * 128 +
                                                    ((kk * 32 + lk * 8) ^ (lr8 << 3))];
          sacc[n] = MFMA16x16x32(aq[kk], bk, sacc[n]);
        }
      }

      // scale + causal mask + online softmax (in-place in sacc)
      float pm[4];
#pragma unroll
      for (int i = 0; i < 4; ++i) pm[i] = -1e30f;
#pragma unroll
      for (int n = 0; n < 4; ++n) {
        const int colg = kv0 + n * 16 + lr;
#pragma unroll
        for (int i = 0; i < 4; ++i) {
          float vsc = sacc[n][i] * scale;
          if (colg > rowg0 + i) vsc = -1e30f;
          sacc[n][i] = vsc;
          pm[i] = fmaxf(pm[i], vsc);
        }
      }
#pragma unroll
      for (int i = 0; i < 4; ++i) {
        pm[i] = fmaxf(pm[i], __shfl_xor(pm[i], 1));
        pm[i] = fmaxf(pm[i], __shfl_xor(pm[i], 2));
        pm[i] = fmaxf(pm[i], __shfl_xor(pm[i], 4));
        pm[i] = fmaxf(pm[i], __shfl_xor(pm[i], 8));
      }
      float alpha[4], rs[4];
#pragma unroll
      for (int i = 0; i < 4; ++i) {
        const float mn = fmaxf(m_i[i], pm[i]);
        alpha[i] = __expf(m_i[i] - mn);
        m_i[i] = mn;
        rs[i] = 0.0f;
      }
#pragma unroll
      for (int n = 0; n < 4; ++n) {
#pragma unroll
        for (int i = 0; i < 4; ++i) {
          const float p = __expf(sacc[n][i] - m_i[i]);
          rs[i] += p;
          const int prow = lk * 4 + i;
          Ps[w][prow * 64 + ((n * 16 + lr) ^ ((prow & 7) << 3))] = (__bf16)p;
        }
      }
#pragma unroll
      for (int i = 0; i < 4; ++i) {
        rs[i] += __shfl_xor(rs[i], 1);
        rs[i] += __shfl_xor(rs[i], 2);
        rs[i] += __shfl_xor(rs[i], 4);
        rs[i] += __shfl_xor(rs[i], 8);
        l_i[i] = l_i[i] * alpha[i] + rs[i];
      }
#pragma unroll
      for (int f = 0; f < 8; ++f)
#pragma unroll
        for (int i = 0; i < 4; ++i) o[f][i] *= alpha[i];

      // O += P V  (P from per-wave swizzled LDS; V^T swizzled in Vs)
#pragma unroll
      for (int ks = 0; ks < 2; ++ks) {
        const bf16x8 pa =
            *(const bf16x8*)&Ps[w][lr * 64 + ((ks * 32 + lk * 8) ^ (lr8 << 3))];
#pragma unroll
        for (int f = 0; f < 8; ++f) {
          const bf16x8 vb = *(const bf16x8*)&Vs[cur][(f * 16 + lr) * 64 +
                                                     ((ks * 32 + lk * 8) ^ (lr8 << 3))];
          o[f] = MFMA16x16x32(pa, vb, o[f]);
        }
      }
    }

    __syncthreads();  // drains vmcnt (next tile staged) + all LDS reads done
  }

  // epilogue: normalize, v-projection correction, store bf16
#pragma unroll
  for (int i = 0; i < 4; ++i) {
    const int sg = rowg0 + i;
    const size_t mg = rb + sg;
    const __bf16* vp = qkv + mg * 3072 + 2560 + kvh * 128;
    const float invl = 1.0f / l_i[i];
    float vvv[8], yvv[8];
    float dyv = 0.0f, dvv = 0.0f;
#pragma unroll
    for (int f = 0; f < 8; ++f) {
      const float vf = (float)vp[f * 16 + lr];
      const float yf = o[f][i] * invl;
      vvv[f] = vf;
      yvv[f] = yf;
      dyv += yf * vf;
      dvv += vf * vf;
    }
#pragma unroll
    for (int off = 1; off < 16; off <<= 1) {
      dyv += __shfl_xor(dyv, off);
      dvv += __shfl_xor(dvv, off);
    }
    const float proj = dyv / fmaxf(dvv, 1e-6f);
    __bf16* yp = y + mg * 2048 + h * 128;
#pragma unroll
    for (int f = 0; f < 8; ++f) yp[f * 16 + lr] = (__bf16)(yvv[f] - proj * vvv[f]);
  }
}

// ---------------------------------------------------------------------------
extern "C" void kernel_launch(void* const* d_in, const int* in_sizes, int n_in,
                              void* d_out, int out_size, void* d_ws, size_t ws_size,
                              hipStream_t stream) {
  const float* x = (const float*)d_in[0];
  const float* Wq = (const float*)d_in[2];
  const float* Wk = (const float*)d_in[3];
  const float* Wv = (const float*)d_in[4];
  const float* Wp = (const float*)d_in[5];
  float* out = (float*)d_out;

  __bf16* xb = (__bf16*)d_ws;                // 4096x2048
  __bf16* Wb = xb + (size_t)4096 * 2048;     // 3072x2048  [Wq;Wk;Wv]
  __bf16* Wpb = Wb + (size_t)3072 * 2048;    // 2048x2048
  __bf16* qkv = Wpb + (size_t)2048 * 2048;   // 4096x3072
  __bf16* yb = qkv + (size_t)4096 * 3072;    // 4096x2048
  __bf16* vt = xb;  // reuse xb region after qkv GEMM (4*4*128*1024 elems)

  cast_f2b<<<1024, 256, 0, stream>>>(x, xb, 4096 * 2048 / 4);
  cast3_f2b<<<768, 256, 0, stream>>>(Wq, Wk, Wv, Wb);
  cast_f2b<<<512, 256, 0, stream>>>(Wp, Wpb, 2048 * 2048 / 4);

  gemm_bt<__bf16><<<dim3(32, 24), 256, 0, stream>>>(xb, Wb, qkv, 4096, 3072, 2048);
  normrope<<<20480, 256, 0, stream>>>(qkv);
  vtrans<<<256, 256, 0, stream>>>(qkv, vt);
  attn_fwd<<<512, 512, 0, stream>>>(qkv, vt, yb);
  gemm_bt<float><<<dim3(32, 16), 256, 0, stream>>>(yb, Wpb, out, 4096, 2048, 2048);
}

// Round 6
// 223.575 us; speedup vs baseline: 1.6199x; 1.1094x over previous
//
#include <hip/hip_runtime.h>

// ---------------------------------------------------------------------------
// SelfAttention fused pipeline for MI355X (gfx950)
// B=4 S=1024 DIM=2048 H=16 KV=4 HD=128 ROPE_DIM=64
//
// Stages (all on `stream`):
//  1) casts fp32 -> bf16 (x | Wq,Wk,Wv fused | Wproj)
//  2) gemm_bt: qkv[4096x3072] = xb @ Wcat^T            (bf16 in, bf16 out)
//  3) normrope: RMSNorm + partial RoPE in-place; q rows pre-scaled by
//     (1/sqrt(128))*log2(e) so attention scores are log2-domain for free
//  3b) vtrans: V -> Vt_global[b,kvh][d][kv] (pre-swizzled for LDS staging)
//  4) attn_fwd: causal flash attention + v-proj correction -> y bf16
//     PERSISTENT-BALANCED: 256 blocks (1/CU), each runs q-tiles pr and 7-pr
//     sequentially => exactly 18 kv-iterations per block, no tail.
//  5) gemm_bt: out[4096x2048] = y @ Wproj^T            (bf16 in, fp32 out)
// ---------------------------------------------------------------------------

typedef __attribute__((ext_vector_type(8))) __bf16 bf16x8;
typedef __attribute__((ext_vector_type(4))) __bf16 bf16x4;
typedef __attribute__((ext_vector_type(4))) float f32x4;

static_assert(sizeof(__bf16) == 2, "bf16 size");

#define MFMA16x16x32(a, b, c) __builtin_amdgcn_mfma_f32_16x16x32_bf16((a), (b), (c), 0, 0, 0)

#if __has_builtin(__builtin_amdgcn_exp2f)
#define EXP2(x) __builtin_amdgcn_exp2f(x)
#else
#define EXP2(x) exp2f(x)
#endif

__device__ __forceinline__ void gload_lds16(const void* g, void* l) {
  __builtin_amdgcn_global_load_lds((const __attribute__((address_space(1))) void*)g,
                                   (__attribute__((address_space(3))) void*)l, 16, 0, 0);
}

// ---------------- 1) cast fp32 -> bf16 (vectorized) ----------------
__global__ __launch_bounds__(256) void cast_f2b(const float* __restrict__ in,
                                                __bf16* __restrict__ out, int n4) {
  int i = blockIdx.x * blockDim.x + threadIdx.x;
  const int stride = gridDim.x * blockDim.x;
  for (; i < n4; i += stride) {
    f32x4 v = ((const f32x4*)in)[i];
    bf16x4 o;
    o[0] = (__bf16)v[0];
    o[1] = (__bf16)v[1];
    o[2] = (__bf16)v[2];
    o[3] = (__bf16)v[3];
    ((bf16x4*)out)[i] = o;
  }
}

// fused cast of Wq(2048x2048) | Wk(512x2048) | Wv(512x2048) into Wb concat
__global__ __launch_bounds__(256) void cast3_f2b(const float* __restrict__ wq,
                                                 const float* __restrict__ wk,
                                                 const float* __restrict__ wv,
                                                 __bf16* __restrict__ out) {
  const int n1 = 2048 * 2048 / 4, n2 = 512 * 2048 / 4;
  const int ntot = n1 + 2 * n2;
  int i = blockIdx.x * blockDim.x + threadIdx.x;
  const int stride = gridDim.x * blockDim.x;
  for (; i < ntot; i += stride) {
    const float* src;
    int j = i;
    if (j < n1) {
      src = wq;
    } else if (j < n1 + n2) {
      src = wk;
      j -= n1;
    } else {
      src = wv;
      j -= n1 + n2;
    }
    f32x4 v = ((const f32x4*)src)[j];
    bf16x4 o;
    o[0] = (__bf16)v[0];
    o[1] = (__bf16)v[1];
    o[2] = (__bf16)v[2];
    o[3] = (__bf16)v[3];
    ((bf16x4*)out)[i] = o;
  }
}

// ---------------- 2/5) B^T GEMM, m97 structure ----------------
template <typename CT>
__global__ __launch_bounds__(256) void gemm_bt(const __bf16* __restrict__ A,
                                               const __bf16* __restrict__ B,
                                               CT* __restrict__ C, int M, int N, int K) {
  __shared__ __bf16 As[128 * 32];
  __shared__ __bf16 Bs[128 * 32];
  const int t = threadIdx.x;
  const int l = t & 63, w = t >> 6;
  const int wr = w >> 1, wc = w & 1;
  const int lr = l & 15, lk = l >> 4;
  const int bm = blockIdx.x, bn = blockIdx.y;
  const __bf16* Ab = A + (size_t)bm * 128 * K;
  const __bf16* Bb = B + (size_t)bn * 128 * K;
  const int srow = t >> 2;
  const int scol = (t & 3) << 3;
  f32x4 acc[4][4] = {};

  for (int k0 = 0; k0 < K; k0 += 32) {
    __syncthreads();
    gload_lds16(Ab + (size_t)srow * K + k0 + scol, As + t * 8);
    gload_lds16(Ab + (size_t)(srow + 64) * K + k0 + scol, As + 2048 + t * 8);
    gload_lds16(Bb + (size_t)srow * K + k0 + scol, Bs + t * 8);
    gload_lds16(Bb + (size_t)(srow + 64) * K + k0 + scol, Bs + 2048 + t * 8);
    __syncthreads();

    bf16x8 af[4], bf[4];
#pragma unroll
    for (int m = 0; m < 4; ++m)
      af[m] = *(const bf16x8*)&As[(wr * 64 + m * 16 + lr) * 32 + lk * 8];
#pragma unroll
    for (int n = 0; n < 4; ++n)
      bf[n] = *(const bf16x8*)&Bs[(wc * 64 + n * 16 + lr) * 32 + lk * 8];
#pragma unroll
    for (int m = 0; m < 4; ++m)
#pragma unroll
      for (int n = 0; n < 4; ++n) acc[m][n] = MFMA16x16x32(af[m], bf[n], acc[m][n]);
  }

#pragma unroll
  for (int m = 0; m < 4; ++m) {
    const int row0 = bm * 128 + wr * 64 + m * 16 + lk * 4;
#pragma unroll
    for (int n = 0; n < 4; ++n) {
      const int col = bn * 128 + wc * 64 + n * 16 + lr;
#pragma unroll
      for (int i = 0; i < 4; ++i) C[(size_t)(row0 + i) * N + col] = (CT)acc[m][n][i];
    }
  }
}

// ---------------- 3) RMSNorm + partial RoPE (in place on qkv) ----------------
// q rows additionally scaled by (1/sqrt(128))*log2(e) -> attention scores
// come out of QK^T already in log2 domain (softmax uses exp2 directly).
__global__ __launch_bounds__(256) void normrope(__bf16* __restrict__ qkv) {
  const int w = threadIdx.x >> 6, l = threadIdx.x & 63;
  const int idx = blockIdx.x * 4 + w;
  int m, col0;
  bool isq;
  if (idx < 65536) {
    m = idx >> 4;
    col0 = (idx & 15) << 7;
    isq = true;
  } else {
    const int j = idx - 65536;
    m = j >> 2;
    col0 = 2048 + ((j & 3) << 7);
    isq = false;
  }
  const int s = m & 1023;
  __bf16* p = qkv + (size_t)m * 3072 + col0;
  float v0 = (float)p[l];
  float v1 = (float)p[l + 64];
  float ss = v0 * v0 + v1 * v1;
#pragma unroll
  for (int off = 1; off < 64; off <<= 1) ss += __shfl_xor(ss, off);
  float sc = rsqrtf(ss * (1.0f / 128.0f) + 1.1920928955078125e-07f);
  v0 *= sc;
  v1 *= sc;
  const float other = __shfl_xor(v0, 32);
  const int j = l & 31;
  const float ang = (float)s * powf(10000.0f, -(float)j * 0.03125f);
  const float cs = cosf(ang), sn = sinf(ang);
  float r0;
  if (l < 32)
    r0 = v0 * cs + other * sn;
  else
    r0 = -other * sn + v0 * cs;
  if (isq) {
    const float qs = 0.1275174457f;  // (1/sqrt(128)) * log2(e)
    r0 *= qs;
    v1 *= qs;
  }
  p[l] = (__bf16)r0;
  p[l + 64] = (__bf16)v1;
}

// ---------------- 3b) V transpose: Vt[b,kvh][d][kv ^ ((d&7)<<3)] -------------
__global__ __launch_bounds__(256) void vtrans(const __bf16* __restrict__ qkv,
                                              __bf16* __restrict__ vt) {
  __shared__ __bf16 L[64 * 128];
  const int tile = blockIdx.x;  // (b*4+kvh)*16 + st
  const int st = tile & 15, bk = tile >> 4;
  const int b = bk >> 2, kvh = bk & 3;
  const int t = threadIdx.x;
  const int s0 = st * 64;
  const __bf16* src = qkv + ((size_t)(b * 1024 + s0)) * 3072 + 2560 + kvh * 128;
#pragma unroll
  for (int r = 0; r < 4; ++r) {
    const int off = r * 2048 + t * 8;
    const int s = off >> 7, d = off & 127;
    bf16x8 v = *(const bf16x8*)(src + (size_t)s * 3072 + d);
    *(bf16x8*)&L[s * 128 + (d ^ ((s & 7) << 3) ^ (((s >> 3) & 7) << 3))] = v;
  }
  __syncthreads();
  __bf16* dst = vt + (size_t)bk * 128 * 1024;
#pragma unroll
  for (int r = 0; r < 4; ++r) {
    const int off = r * 2048 + t * 8;
    const int d = off >> 6, sc = off & 63;
    bf16x8 v;
#pragma unroll
    for (int j = 0; j < 8; ++j) {
      const int s = sc + j;
      v[j] = L[s * 128 + (d ^ ((s & 7) << 3) ^ (((s >> 3) & 7) << 3))];
    }
    *(bf16x8*)&dst[(size_t)d * 1024 + ((s0 + sc) ^ ((d & 7) << 3))] = v;
  }
}

// ---------------- 4) causal flash attention + v-projection correction ------
// 256 blocks (=1/CU), each handles ONE (b,h) and TWO q-tiles (pr, 7-pr)
// sequentially -> exactly 18 kv-iterations/block: structurally uniform load
// independent of dispatch order. XCD grouping: blocks of one (b,kvh) group
// share an XCD (id&7) so K/V (~512 KB/group, 2 groups/XCD) stays L2-resident.
// Per pass: 128 q-rows, 8 waves x 16 rows; Q in regs; K/V double-buffered in
// swizzled LDS; stage(t+1) issued before compute(t). Scores arrive log2-domain
// (q pre-scaled in normrope) -> single v_exp per softmax element; causal mask
// evaluated only on diagonal-overlapping tiles.
__global__ __launch_bounds__(512) void attn_fwd(const __bf16* __restrict__ qkv,
                                                const __bf16* __restrict__ vt,
                                                __bf16* __restrict__ y) {
  const int id = blockIdx.x;
  const int g = (id & 7) | (((id >> 3) & 1) << 3);  // (b,kvh) group 0..15
  const int b = g >> 2, kvh = g & 3;
  const int hi = (id >> 4) & 3;
  const int pr = (id >> 6) & 3;
  const int h = kvh * 4 + hi;

  const int t = threadIdx.x;
  const int l = t & 63, w = t >> 6;  // 8 waves
  const int lr = l & 15, lk = l >> 4;
  const int lr8 = lr & 7;

  __shared__ __bf16 Ks[2][64 * 128];
  __shared__ __bf16 Vs[2][128 * 64];
  __shared__ __bf16 Ps[8][16 * 64];

  const size_t rb = (size_t)b * 1024;
  const __bf16* Kg0 = qkv + rb * 3072 + 2048 + kvh * 128;
  const __bf16* Vtb = vt + (size_t)(b * 4 + kvh) * 128 * 1024;

  // staging address constants
  const int koff0 = t * 8;
  const int krow0 = koff0 >> 7;
  const int kcol0 = (koff0 & 127) ^ ((krow0 & 7) << 3);
  const int koff1 = 4096 + t * 8;
  const int krow1 = koff1 >> 7;
  const int kcol1 = (koff1 & 127) ^ ((krow1 & 7) << 3);
  const int voff0 = t * 8, voff1 = 4096 + t * 8;

#pragma unroll 1
  for (int pass = 0; pass < 2; ++pass) {
    const int qt = pass ? (7 - pr) : pr;
    const int q0 = qt << 7;

    // Q fragments -> registers; wave w owns q-rows q0+w*16..+15
    bf16x8 aq[4];
    {
      const __bf16* qrow = qkv + (rb + q0 + w * 16 + lr) * 3072 + h * 128 + lk * 8;
#pragma unroll
      for (int kk = 0; kk < 4; ++kk) aq[kk] = *(const bf16x8*)(qrow + kk * 32);
    }

    float m_i[4], l_i[4];
    f32x4 o[8] = {};
#pragma unroll
    for (int i = 0; i < 4; ++i) {
      m_i[i] = -1e30f;
      l_i[i] = 0.0f;
    }

    const int rowg0 = q0 + w * 16 + lk * 4;
    const int wmin = q0 + w * 16;
    const int wmax = wmin + 15;
    const int nt = 2 * qt + 2;

    // prologue: stage tile 0 into buf 0 (prior pass's LDS reads all done:
    // every wave passed the previous loop's final barrier before reaching here)
    gload_lds16(Kg0 + (size_t)krow0 * 3072 + kcol0, &Ks[0][0] + koff0);
    gload_lds16(Kg0 + (size_t)krow1 * 3072 + kcol1, &Ks[0][0] + koff1);
    gload_lds16(Vtb + (size_t)(voff0 >> 6) * 1024 + (voff0 & 63), &Vs[0][0] + voff0);
    gload_lds16(Vtb + (size_t)(voff1 >> 6) * 1024 + (voff1 & 63), &Vs[0][0] + voff1);
    __syncthreads();  // drains vmcnt -> buf0 ready

    for (int tt = 0; tt < nt; ++tt) {
      const int kv0 = tt * 64;
      const int cur = tt & 1;
      // issue next tile's staging first (async; lands in other buffer)
      if (tt + 1 < nt) {
        const int nkv = kv0 + 64;
        const __bf16* Kg = Kg0 + (size_t)nkv * 3072;
        __bf16* kd = &Ks[cur ^ 1][0];
        __bf16* vd = &Vs[cur ^ 1][0];
        gload_lds16(Kg + (size_t)krow0 * 3072 + kcol0, kd + koff0);
        gload_lds16(Kg + (size_t)krow1 * 3072 + kcol1, kd + koff1);
        gload_lds16(Vtb + (size_t)(voff0 >> 6) * 1024 + nkv + (voff0 & 63), vd + voff0);
        gload_lds16(Vtb + (size_t)(voff1 >> 6) * 1024 + nkv + (voff1 & 63), vd + voff1);
      }

      if (kv0 <= wmax) {  // wave has unmasked work in this tile
        // S = Q K^T (log2-domain: q pre-scaled in normrope)
        f32x4 sacc[4] = {};
#pragma unroll
        for (int kk = 0; kk < 4; ++kk) {
#pragma unroll
          for (int n = 0; n < 4; ++n) {
            const bf16x8 bk = *(const bf16x8*)&Ks[cur][(n * 16 + lr) * 128 +
                                                      ((kk * 32 + lk * 8) ^ (lr8 << 3))];
            sacc[n] = MFMA16x16x32(aq[kk], bk, sacc[n]);
          }
        }

        // causal mask (diagonal tiles only) + online softmax (exp2)
        float pm[4];
#pragma unroll
        for (int i = 0; i < 4; ++i) pm[i] = -1e30f;
        if (kv0 + 63 > wmin) {  // tile overlaps diagonal: mask needed
#pragma unroll
          for (int n = 0; n < 4; ++n) {
            const int colg = kv0 + n * 16 + lr;
#pragma unroll
            for (int i = 0; i < 4; ++i) {
              if (colg > rowg0 + i) sacc[n][i] = -1e30f;
              pm[i] = fmaxf(pm[i], sacc[n][i]);
            }
          }
        } else {
#pragma unroll
          for (int n = 0; n < 4; ++n)
#pragma unroll
            for (int i = 0; i < 4; ++i) pm[i] = fmaxf(pm[i], sacc[n][i]);
        }
#pragma unroll
        for (int i = 0; i < 4; ++i) {
          pm[i] = fmaxf(pm[i], __shfl_xor(pm[i], 1));
          pm[i] = fmaxf(pm[i], __shfl_xor(pm[i], 2));
          pm[i] = fmaxf(pm[i], __shfl_xor(pm[i], 4));
          pm[i] = fmaxf(pm[i], __shfl_xor(pm[i], 8));
        }
        float alpha[4], rs[4];
#pragma unroll
        for (int i = 0; i < 4; ++i) {
          const float mn = fmaxf(m_i[i], pm[i]);
          alpha[i] = EXP2(m_i[i] - mn);
          m_i[i] = mn;
          rs[i] = 0.0f;
        }
#pragma unroll
        for (int n = 0; n < 4; ++n) {
#pragma unroll
          for (int i = 0; i < 4; ++i) {
            const float p = EXP2(sacc[n][i] - m_i[i]);
            rs[i] += p;
            const int prow = lk * 4 + i;
            Ps[w][prow * 64 + ((n * 16 + lr) ^ ((prow & 7) << 3))] = (__bf16)p;
          }
        }
#pragma unroll
        for (int i = 0; i < 4; ++i) {
          rs[i] += __shfl_xor(rs[i], 1);
          rs[i] += __shfl_xor(rs[i], 2);
          rs[i] += __shfl_xor(rs[i], 4);
          rs[i] += __shfl_xor(rs[i], 8);
          l_i[i] = l_i[i] * alpha[i] + rs[i];
        }
#pragma unroll
        for (int f = 0; f < 8; ++f)
#pragma unroll
          for (int i = 0; i < 4; ++i) o[f][i] *= alpha[i];

        // O += P V  (P from per-wave swizzled LDS; V^T swizzled in Vs)
#pragma unroll
        for (int ks = 0; ks < 2; ++ks) {
          const bf16x8 pa =
              *(const bf16x8*)&Ps[w][lr * 64 + ((ks * 32 + lk * 8) ^ (lr8 << 3))];
#pragma unroll
          for (int f = 0; f < 8; ++f) {
            const bf16x8 vb = *(const bf16x8*)&Vs[cur][(f * 16 + lr) * 64 +
                                                       ((ks * 32 + lk * 8) ^ (lr8 << 3))];
            o[f] = MFMA16x16x32(pa, vb, o[f]);
          }
        }
      }

      __syncthreads();  // next tile staged (vmcnt drained) + all LDS reads done
    }

    // epilogue: normalize, v-projection correction, store bf16 (LDS-free)
#pragma unroll
    for (int i = 0; i < 4; ++i) {
      const int sg = rowg0 + i;
      const size_t mg = rb + sg;
      const __bf16* vp = qkv + mg * 3072 + 2560 + kvh * 128;
      const float invl = 1.0f / l_i[i];
      float vvv[8], yvv[8];
      float dyv = 0.0f, dvv = 0.0f;
#pragma unroll
      for (int f = 0; f < 8; ++f) {
        const float vf = (float)vp[f * 16 + lr];
        const float yf = o[f][i] * invl;
        vvv[f] = vf;
        yvv[f] = yf;
        dyv += yf * vf;
        dvv += vf * vf;
      }
#pragma unroll
      for (int off = 1; off < 16; off <<= 1) {
        dyv += __shfl_xor(dyv, off);
        dvv += __shfl_xor(dvv, off);
      }
      const float proj = dyv / fmaxf(dvv, 1e-6f);
      __bf16* yp = y + mg * 2048 + h * 128;
#pragma unroll
      for (int f = 0; f < 8; ++f) yp[f * 16 + lr] = (__bf16)(yvv[f] - proj * vvv[f]);
    }
  }
}

// ---------------------------------------------------------------------------
extern "C" void kernel_launch(void* const* d_in, const int* in_sizes, int n_in,
                              void* d_out, int out_size, void* d_ws, size_t ws_size,
                              hipStream_t stream) {
  const float* x = (const float*)d_in[0];
  const float* Wq = (const float*)d_in[2];
  const float* Wk = (const float*)d_in[3];
  const float* Wv = (const float*)d_in[4];
  const float* Wp = (const float*)d_in[5];
  float* out = (float*)d_out;

  __bf16* xb = (__bf16*)d_ws;                // 4096x2048
  __bf16* Wb = xb + (size_t)4096 * 2048;     // 3072x2048  [Wq;Wk;Wv]
  __bf16* Wpb = Wb + (size_t)3072 * 2048;    // 2048x2048
  __bf16* qkv = Wpb + (size_t)2048 * 2048;   // 4096x3072
  __bf16* yb = qkv + (size_t)4096 * 3072;    // 4096x2048
  __bf16* vt = xb;  // reuse xb region after qkv GEMM (4*4*128*1024 elems)

  cast_f2b<<<1024, 256, 0, stream>>>(x, xb, 4096 * 2048 / 4);
  cast3_f2b<<<768, 256, 0, stream>>>(Wq, Wk, Wv, Wb);
  cast_f2b<<<512, 256, 0, stream>>>(Wp, Wpb, 2048 * 2048 / 4);

  gemm_bt<__bf16><<<dim3(32, 24), 256, 0, stream>>>(xb, Wb, qkv, 4096, 3072, 2048);
  normrope<<<20480, 256, 0, stream>>>(qkv);
  vtrans<<<256, 256, 0, stream>>>(qkv, vt);
  attn_fwd<<<256, 512, 0, stream>>>(qkv, vt, yb);
  gemm_bt<float><<<dim3(32, 16), 256, 0, stream>>>(yb, Wpb, out, 4096, 2048, 2048);
}